// Round 13
// baseline (810.645 us; speedup 1.0000x reference)
//
#include <hip/hip_runtime.h>
#include <math.h>

#define T_STEPS 256
#define BATCH   256
#define DDIM    128
#define NH      10

typedef float v2f __attribute__((ext_vector_type(2)));
typedef int   v2i __attribute__((ext_vector_type(2)));
__device__ __forceinline__ v2f sp(float x){ v2f r; r.x = x; r.y = x; return r; }
#define PKFMA(a,b,c) __builtin_elementwise_fma((a),(b),(c))

// ---------- DPP helpers (VALU pipe) ----------
template<int CTRL, int RMASK, int BMASK>
__device__ __forceinline__ float dppz(float x){
  return __int_as_float(__builtin_amdgcn_update_dpp(
      0, __float_as_int(x), CTRL, RMASK, BMASK, true));
}
template<int CTRL>
__device__ __forceinline__ float qperm(float x){
  int xi = __float_as_int(x);
  return __int_as_float(__builtin_amdgcn_update_dpp(xi, xi, CTRL, 0xF, 0xF, false));
}
__device__ __forceinline__ float rdlane(float v, int l){
  return __int_as_float(__builtin_amdgcn_readlane(__float_as_int(v), l));
}
// quad-perm xor (1 DPP): xor2 = 0x4E, xor1 = 0xB1 (proven baseline/R5)
__device__ __forceinline__ float qp2(float x){ return qperm<0x4E>(x); }
__device__ __forceinline__ float qp1(float x){ return qperm<0xB1>(x); }
// xor-4 / xor-8 within a 16-lane row, 2 DPP (proven baseline/R1)
__device__ __forceinline__ float lane_xor4(float x){
  int xi = __float_as_int(x);
  int t = __builtin_amdgcn_update_dpp(xi, xi, 0x104, 0xF, 0x5, false); // row_shl:4, banks {0,2}
  t     = __builtin_amdgcn_update_dpp(t,  xi, 0x114, 0xF, 0xA, false); // row_shr:4, banks {1,3}
  return __int_as_float(t);
}
__device__ __forceinline__ float lane_xor8(float x){
  int xi = __float_as_int(x);
  int t = __builtin_amdgcn_update_dpp(xi, xi, 0x108, 0xF, 0x3, false); // row_shl:8, banks {0,1}
  t     = __builtin_amdgcn_update_dpp(t,  xi, 0x118, 0xF, 0xC, false); // row_shr:8, banks {2,3}
  return __int_as_float(t);
}
// xor16 via permlane16_swap (VALU pipe, no LDS traffic). With both operands
// = x the result pair {r.x, r.y} holds {own, partner} in SOME order at every
// lane, so partner = r.x ^ r.y ^ own — direction-agnostic, bit-exact
// (HW-proven in R1 and R10 passed runs).
#if __has_builtin(__builtin_amdgcn_permlane16_swap)
__device__ __forceinline__ float plx16(float x){
  int xi = __float_as_int(x);
  v2i r = __builtin_amdgcn_permlane16_swap(xi, xi, false, false);
  return __int_as_float(r.x ^ r.y ^ xi);
}
#else
__device__ __forceinline__ float plx16(float x){
  return __int_as_float(__builtin_amdgcn_ds_swizzle(__float_as_int(x), 0x401F));
}
#endif

// ---------- signed ladder stages (totals land at lane 63; proven R3) ----------
template<int CTRL,int RMASK,int BMASK>
__device__ __forceinline__ float lad_add(float v){ return v + dppz<CTRL,RMASK,BMASK>(v); }
template<int CTRL,int RMASK,int BMASK>
__device__ __forceinline__ float lad_sub(float v){ return dppz<CTRL,RMASK,BMASK>(v) - v; }
#define LAD0_A(v) lad_add<0x111,0xF,0xF>(v)
#define LAD0_S(v) lad_sub<0x111,0xF,0xF>(v)
#define LAD1_A(v) lad_add<0x112,0xF,0xF>(v)
#define LAD1_S(v) lad_sub<0x112,0xF,0xF>(v)
#define LAD2_A(v) lad_add<0x114,0xF,0xE>(v)
#define LAD2_S(v) lad_sub<0x114,0xF,0xE>(v)
#define LAD3_A(v) lad_add<0x118,0xF,0xC>(v)
#define LAD3_S(v) lad_sub<0x118,0xF,0xC>(v)
#define LAD4_A(v) lad_add<0x142,0xA,0xF>(v)
#define LAD4_S(v) lad_sub<0x142,0xA,0xF>(v)
#define LAD5_A(v) lad_add<0x143,0xC,0xF>(v)
#define LAD5_S(v) lad_sub<0x143,0xC,0xF>(v)

// ---------- ds-pipe fetchers (ONLY in the shadow xdots, waits hidden) ----------
__device__ __forceinline__ float dsx32(float x){ return __shfl_xor(x, 32, 64); }
__device__ __forceinline__ float dsx16(float x){
  return __int_as_float(__builtin_amdgcn_ds_swizzle(__float_as_int(x), 0x401F));
}

#define NK 4   // 4 packed pairs = 8 complex amps per lane (half statevector)

// ---- tau-form RX: cosines folded into phase constants; ONE pk-FMA/output.
#define RX_LANE_T(FETCH, tv)                                                   \
  { const v2f tt_ = sp(tv), nt_ = sp(-(tv));                                   \
    _Pragma("unroll")                                                          \
    for (int k = 0; k < NK; ++k){                                              \
      v2f oa, ob;                                                              \
      oa.x = FETCH(RE[k].x); oa.y = FETCH(RE[k].y);                            \
      ob.x = FETCH(IM[k].x); ob.y = FETCH(IM[k].y);                            \
      RE[k] = PKFMA(tt_, ob, RE[k]);                                           \
      IM[k] = PKFMA(nt_, oa, IM[k]);                                           \
    } }

// RX on reg bit R2 (XB=2) / R1 (XB=1): partner pair is k^XB.
template<int XB>
__device__ __forceinline__ void rx_reg_t(float tv, v2f* RE, v2f* IM){
  const v2f tt = sp(tv), nt = sp(-tv);
  v2f oR[NK], oI[NK];
  #pragma unroll
  for (int k = 0; k < NK; ++k){ oR[k] = RE[k]; oI[k] = IM[k]; }
  #pragma unroll
  for (int k = 0; k < NK; ++k){
    RE[k] = PKFMA(tt, oI[k ^ XB], RE[k]);
    IM[k] = PKFMA(nt, oR[k ^ XB], IM[k]);
  }
}
// RX on reg bit R0: partner is the swapped component of the same pair.
__device__ __forceinline__ void rx_reg9_t(float tv, v2f* RE, v2f* IM){
  const v2f tt = sp(tv), nt = sp(-tv);
  #pragma unroll
  for (int k = 0; k < NK; ++k){
    v2f oa = __builtin_shufflevector(RE[k], RE[k], 1, 0);
    v2f ob = __builtin_shufflevector(IM[k], IM[k], 1, 0);
    RE[k] = PKFMA(tt, ob, RE[k]);
    IM[k] = PKFMA(nt, oa, IM[k]);
  }
}

// 5-value wave-sum merge tree, hybrid transport (R11; ds RTs hide under the
// independent measurement tree). Full sums: v0@{l5=0,l4=0,l3=0},
// v1@{l5=1,l4=0,l3=0}, v2@{l5=0,l4=1,l3=0}, v3@{l5=1,l4=1,l3=0}, v4@{l3=1}.
__device__ __forceinline__ void xdots5(float xa, float xb,
                                       const v2f* WA, const v2f* WB,
                                       int l5, int l4, int l3, float* s){
  v2f xav = sp(xa), xbv = sp(xb);
  v2f p0 = PKFMA(xav, WA[0], xbv * WB[0]);
  v2f p1 = PKFMA(xav, WA[1], xbv * WB[1]);
  v2f p2 = PKFMA(xav, WA[2], xbv * WB[2]);
  float a  = p0.x + dsx32(p0.x);
  float bv = p0.y + dsx32(p0.y);
  float c  = p1.x + dsx32(p1.x);
  float d  = p1.y + dsx32(p1.y);
  float e  = p2.x + dsx32(p2.x);
  float m1 = l5 ? bv : a;
  float m2 = l5 ? d : c;
  m1 += dsx16(m1);
  m2 += dsx16(m2);
  e  += dsx16(e);
  float n1 = l4 ? m2 : m1;
  n1 += lane_xor8(n1);
  e  += lane_xor8(e);
  float p = l3 ? e : n1;
  p += lane_xor4(p);
  p += qp2(p);
  p += qp1(p);
  s[0] = rdlane(p, 0);
  s[1] = rdlane(p, 32);
  s[2] = rdlane(p, 16);
  s[3] = rdlane(p, 48);
  s[4] = rdlane(p, 8);
}

// ================= R13 layout =================
// Wave pair per gate: 512 amps/wave = 64 lanes x 8 regs (4 v2f pairs).
// Wires 0..5 -> lane bits 5..0, wire 6 -> wave bit, wires 7,8,9 -> reg bits
// 2,1,0 (R0 = packed component). 1 barrier/step.
// R12: wires 6 AND 0 folded into a 4-term build (own, W-flip, L5-flip, both)
// with init-time D6/D0/D60 constants; build selects via readlane+cndmask.
// R13: the last RX ds stage (wire 1, xor16) moves to the permlane16 xor
// trick -> the ENTIRE RX chain is register/VALU with zero lgkm waits. The
// only remaining ds traffic: shadow xdots (hidden) + partials at the barrier.
__global__ void __launch_bounds__(512)
__attribute__((amdgpu_waves_per_eu(2)))
qlstm_kernel(const float* __restrict__ inp, const float* __restrict__ rxp,
             const float* __restrict__ Wf, const float* __restrict__ bf,
             const float* __restrict__ Wi, const float* __restrict__ bi,
             const float* __restrict__ Wg, const float* __restrict__ bg,
             const float* __restrict__ Wo, const float* __restrict__ bo,
             float* __restrict__ out)
{
  const int b    = blockIdx.x;
  const int tid  = threadIdx.x;
  const int wv   = tid >> 6;        // 0..7
  const int g    = wv >> 1;         // gate 0..3 (f,i,g,o)
  const int half = wv & 1;          // statevector half (wire-6 / wave bit)
  const int lane = tid & 63;

  // measurement partials, transposed: partv[half][j].{x,y,z,w} = gate f,i,g,o
  __shared__ float4 partv[2][64];
  // published x-part pre-activations (incl. bias), xpub_s[g][wire]
  __shared__ float xpub_s[4][16];
  ((float*)partv)[tid] = 0.f;       // 2*64*4 = 512 = blockDim
  if (tid < 64) ((float*)xpub_s)[tid] = 0.f;

  const float* Wp = (g == 0) ? Wf : (g == 1) ? Wi : (g == 2) ? Wg : Wo;
  const float* bp = (g == 0) ? bf : (g == 1) ? bi : (g == 2) ? bg : bo;

  // Pre-scale weights by 0.5 (half-angle) * 1/(2pi) (v_cos takes revolutions).
  const float WSC = 0.07957747154594767f;   // 1/(4*pi)

  // x-dot weights for this half's 5 owned wires (wbase..wbase+4)
  const int wbase = half * 5;
  v2f WA[3], WB[3];
  float bq[5];
  #pragma unroll
  for (int k = 0; k < 5; ++k) bq[k] = WSC * (bp[wbase + k] + rxp[wbase + k]);
  #pragma unroll
  for (int j = 0; j < 3; ++j){
    const int w0 = wbase + 2*j, w1 = wbase + 2*j + 1;
    WA[j].x = WSC * Wp[w0*138 + lane];
    WB[j].x = WSC * Wp[w0*138 + 64 + lane];
    if (2*j + 1 < 5){
      WA[j].y = WSC * Wp[w1*138 + lane];
      WB[j].y = WSC * Wp[w1*138 + 64 + lane];
    } else { WA[j].y = 0.f; WB[j].y = 0.f; }
  }
  // transposed h-weights: lane w AND lane 16+w hold W[w][128+j] (the high
  // group recomputes the same th for the sin path).
  const int trigAct = (lane < NH) || (lane >= 16 && lane < 16 + NH);
  float wCT[NH];
  {
    const int row = trigAct ? (lane & 15) : 0;
    #pragma unroll
    for (int j = 0; j < NH; ++j){
      float v = WSC * Wp[row*138 + 128 + j];
      wCT[j] = trigAct ? v : 0.f;
    }
  }
  // sin shift: lanes with bit4 set evaluate cos(th - 0.25rev) = sin(th)
  const float shift = ((lane >> 4) & 1) ? -0.25f : 0.f;

  // tau-form RX constants: tq[w] = tan(rxp[w]/2); PC = prod cos(rxp[w]/2)
  float tq[NH];
  float PC = 1.f;
  #pragma unroll
  for (int w = 0; w < NH; ++w){
    float th = 0.5f * rxp[w];
    float cw = cosf(th), sw = sinf(th);
    PC *= cw;
    tq[w] = sw / cw;
  }

  // ---- hoisted lane/wave constants ----
  const int l5 = (lane>>5)&1, l4 = (lane>>4)&1, l3 = (lane>>3)&1;
  const int l2 = (lane>>2)&1, l1 = (lane>>1)&1, l0 = lane&1;
  const int pb2 = l4^l3, pb3 = l3^l2, pb4 = l2^l1, pb5 = l1^l0;
  const int a0 = l5, a1 = l5^l4;
  const int a6w = l0 ^ half;                       // beta6
  const int n_base = pb2 + pb3 + pb4 + pb5 + a6w;

  // phase constants (-i)^k per reg (step-invariant), packed over R0, scaled
  // by PC. Fold constants for the two pre-applied rotations:
  //   D6*: wire-6 (wave-bit) partner, sign s6 = (l0^R2)? + : -  [R7-proven]
  //   D0*: wire-0 (L5) partner,      sign s0 = l4? + : -
  //   D60*: both flipped, factor -tau6*tau0*s6*s0 on (CRE,CIM)
  v2f CRE[NK], CIM[NK], D6RE[NK], D6IM[NK];
  v2f D0RE[NK], D0IM[NK], D60RE[NK], D60IM[NK];
  #pragma unroll
  for (int r = 0; r < 2*NK; ++r){
    const int R0 = r&1, R1 = (r>>1)&1, R2 = (r>>2)&1;
    int k = (n_base + (a0^R0) + (a1^R0) + (half^R2) + (R2^R1) + (R1^R0)) & 3;
    float cr = (k==0) ? PC : (k==2) ? -PC : 0.f;
    float ci = (k==1) ? -PC : (k==3) ? PC : 0.f;
    float s6s = ((l0 ^ R2) & 1) ? 1.f : -1.f;
    float s0s = l4 ? 1.f : -1.f;
    float d6re =  tq[6]*s6s*ci,  d6im = -tq[6]*s6s*cr;
    float d0re =  tq[0]*s0s*ci,  d0im = -tq[0]*s0s*cr;
    float t60  = -tq[6]*tq[0]*s6s*s0s;
    float d60re = t60*cr, d60im = t60*ci;
    if (R0){ CRE[r>>1].y = cr;   CIM[r>>1].y = ci;
             D6RE[r>>1].y = d6re; D6IM[r>>1].y = d6im;
             D0RE[r>>1].y = d0re; D0IM[r>>1].y = d0im;
             D60RE[r>>1].y = d60re; D60IM[r>>1].y = d60im; }
    else   { CRE[r>>1].x = cr;   CIM[r>>1].x = ci;
             D6RE[r>>1].x = d6re; D6IM[r>>1].x = d6im;
             D0RE[r>>1].x = d0re; D0IM[r>>1].x = d0im;
             D60RE[r>>1].x = d60re; D60IM[r>>1].x = d60im; }
  }

  // wave-sign at combine: sigma = -1 for hidden units {0, 6..9}
  const float sig = (lane == 0 || lane >= 6) ? -1.f : 1.f;

  float h = 0.f, c = 0.f;   // lane j holds h_j, c_j redundantly in every wave

  const float* x0 = inp + (size_t)b * DDIM;
  float xa = x0[lane];
  float xb = x0[64 + lane];

  // publish x-part pre-activations for step 0
  {
    float sx[5];
    xdots5(xa, xb, WA, WB, l5, l4, l3, sx);
    if (lane == 63){
      #pragma unroll
      for (int k = 0; k < 5; ++k) xpub_s[g][wbase + k] = sx[k] + bq[k];
    }
  }
  __syncthreads();

  #pragma unroll 1
  for (int t = 0; t < T_STEPS; ++t){
    if (t + 1 < T_STEPS){
      const float* nx = inp + ((size_t)(t+1) * BATCH + b) * DDIM;
      xa = nx[lane];
      xb = nx[64 + lane];
    }

    // ---- angles: lanes 0..9 -> cos, lanes 16..25 -> sin (same th, -0.25) ----
    float cA;
    {
      float xr = xpub_s[g][lane & 15];
      float hdA = rdlane(h, 0) * wCT[0];
      float hdB = rdlane(h, 1) * wCT[1];
      hdA = fmaf(rdlane(h, 2), wCT[2], hdA);
      hdB = fmaf(rdlane(h, 3), wCT[3], hdB);
      hdA = fmaf(rdlane(h, 4), wCT[4], hdA);
      hdB = fmaf(rdlane(h, 5), wCT[5], hdB);
      hdA = fmaf(rdlane(h, 6), wCT[6], hdA);
      hdB = fmaf(rdlane(h, 7), wCT[7], hdB);
      hdA = fmaf(rdlane(h, 8), wCT[8], hdA);
      hdB = fmaf(rdlane(h, 9), wCT[9], hdB);
      float th = (xr + (hdA + hdB)) + shift;
      cA = __builtin_amdgcn_cosf(th);
    }

    // ---- build factors via readlane selects (no ds round trip) ----
    float cs0 = rdlane(cA, 0), sn0 = rdlane(cA, 16);
    float cs1 = rdlane(cA, 1), sn1 = rdlane(cA, 17);
    float cs2 = rdlane(cA, 2), sn2 = rdlane(cA, 18);
    float cs3 = rdlane(cA, 3), sn3 = rdlane(cA, 19);
    float cs4 = rdlane(cA, 4), sn4 = rdlane(cA, 20);
    float cs5 = rdlane(cA, 5), sn5 = rdlane(cA, 21);
    float cs6 = rdlane(cA, 6), sn6 = rdlane(cA, 22);
    float f2  = pb2 ? sn2 : cs2;
    float f3  = pb3 ? sn3 : cs3;
    float f4  = pb4 ? sn4 : cs4;
    float f5  = pb5 ? sn5 : cs5;
    float w6o = a6w ? sn6 : cs6;
    float w6p = a6w ? cs6 : sn6;
    float q0  = (a0 ? sn0 : cs0) * (a1 ? sn1 : cs1);
    float q1  = (a0 ? cs0 : sn0) * (a1 ? cs1 : sn1);
    float m2345b = (f2*f3)*(f4*f5);
    float mo = m2345b * w6o;
    float mp = m2345b * w6p;
    v2f ZZ; ZZ.x = mo * q0; ZZ.y = mo * q1;
    v2f ZP; ZP.x = mp * q0; ZP.y = mp * q1;
    v2f ZZs = __builtin_shufflevector(ZZ, ZZ, 1, 0);   // L5-flip: q0<->q1
    v2f ZPs = __builtin_shufflevector(ZP, ZP, 1, 0);

    float u7  = rdlane(cA, 7 + 16*half);
    float u7b = rdlane(cA, 23 - 16*half);
    float c8  = rdlane(cA, 8);
    float s8  = rdlane(cA, 24);
    float c9  = rdlane(cA, 9);
    float s9  = rdlane(cA, 25);
    float t78[4];
    t78[0] = u7  * c8;   // k=0: R2=0,R1=0
    t78[1] = u7  * s8;   // k=1: R2=0,R1=1
    t78[2] = u7b * s8;   // k=2: R2=1,R1=0
    t78[3] = u7b * c8;   // k=3: R2=1,R1=1
    v2f s9a; s9a.x = c9; s9a.y = s9;   // k even: b9 = R1^R0 = (0,1)
    v2f s9b; s9b.x = s9; s9b.y = c9;   // k odd:  b9 = (1,0)

    // ---- 4-term build: own + wire-6 partner + wire-0 partner + both ----
    v2f RE[NK], IM[NK];
    #pragma unroll
    for (int k = 0; k < NK; ++k){
      v2f s9v = (k & 1) ? s9b : s9a;
      v2f G   = sp(t78[k])     * s9v;
      v2f Gp  = sp(t78[k ^ 3]) * s9v;   // beta7 flip (wire-6 partner)
      v2f M   = G  * ZZ;
      v2f Mp6 = Gp * ZP;
      v2f M0  = G  * ZZs;
      v2f M60 = Gp * ZPs;
      RE[k] = PKFMA(M60, D60RE[k],
              PKFMA(M0,  D0RE[k],
              PKFMA(Mp6, D6RE[k], M * CRE[k])));
      IM[k] = PKFMA(M60, D60IM[k],
              PKFMA(M0,  D0IM[k],
              PKFMA(Mp6, D6IM[k], M * CIM[k])));
    }

    // ---- RX(p), tau-form, FULLY VALU (zero lgkm waits on the chain):
    // wire 1 via permlane16 xor-trick, wires 2..5 DPP, reg wires 7..9 ----
    RX_LANE_T(plx16, tq[1])
    rx_reg_t<2>(tq[7], RE, IM);
    rx_reg_t<1>(tq[8], RE, IM);
    RX_LANE_T(lane_xor8, tq[2])
    rx_reg9_t  (tq[9], RE, IM);
    RX_LANE_T(lane_xor4, tq[3])
    RX_LANE_T(qp2, tq[4])
    RX_LANE_T(qp1, tq[5])

    // ---- shadow: x-part dots for step t+1 (uses prefetched x) ----
    float sx[5];
    xdots5(xa, xb, WA, WB, l5, l4, l3, sx);

    // ---- PauliZ partials: packed |psi|^2 + shared pair-tree ----
    v2f Pk[NK];
    #pragma unroll
    for (int k = 0; k < NK; ++k) Pk[k] = PKFMA(RE[k], RE[k], IM[k] * IM[k]);
    float A0 = Pk[0].x + Pk[0].y, A1 = Pk[1].x + Pk[1].y;
    float A2 = Pk[2].x + Pk[2].y, A3 = Pk[3].x + Pk[3].y;
    float B0 = Pk[0].x - Pk[0].y, B1 = Pk[1].x - Pk[1].y;
    float B2 = Pk[2].x - Pk[2].y, B3 = Pk[3].x - Pk[3].y;
    float su = A0 + A1, sv = A2 + A3;
    float tot = su + sv;                 // plain sum
    float q4  = su - sv;                 // sign on R2
    float q6  = (A0 - A1) - (A2 - A3);   // sign parity of R2^R1 mask 0x6
    float q7  = (B0 - B1) - (B2 - B3);   // sign parity of mask 0x7

    // ---- shared signed-ladder reductions (sign masks encoded as add/sub) ----
    float a0p = LAD0_A(tot);
    float a0m = LAD0_S(tot);
    float b1pp = LAD1_A(a0p);
    float b1pm = LAD1_S(a0p);
    float b1mm = LAD1_S(a0m);
    float c2ppp = LAD2_A(b1pp);
    float c2ppm = LAD2_S(b1pp);
    float c2pmm = LAD2_S(b1pm);
    float c2mmm = LAD2_S(b1mm);
    float d1 = LAD3_A(c2ppp);   // P1: ++++ then --
    float d2 = LAD3_S(c2ppp);   // P2: +++-
    float d3 = LAD3_S(c2ppm);   // P3: ++--
    float d4 = LAD3_S(c2pmm);   // P4: +---
    float d5 = LAD3_S(c2mmm);   // P5: ----
    float P1 = LAD5_S(LAD4_S(d1));
    float P2 = LAD5_S(LAD4_S(d2));
    float P3 = LAD5_S(LAD4_S(d3));
    float P4 = LAD5_S(LAD4_S(d4));
    float P5 = LAD5_S(LAD4_S(d5));   // serves S5 (sigma +) and S6 (sigma -)
    // q7: P9 = all-minus (mask 0x3F); P0 = minus bits0-4, plus bit5 (0x1F)
    float e = LAD0_S(q7);
    e = LAD1_S(e); e = LAD2_S(e); e = LAD3_S(e); e = LAD4_S(e);
    float P9 = LAD5_S(e);
    float P0 = LAD5_A(e);
    // q4, q6: all-minus (mask 0x3F)
    float f_ = LAD0_S(q4);
    f_ = LAD1_S(f_); f_ = LAD2_S(f_); f_ = LAD3_S(f_); f_ = LAD4_S(f_);
    float P7 = LAD5_S(f_);
    float g_ = LAD0_S(q6);
    g_ = LAD1_S(g_); g_ = LAD2_S(g_); g_ = LAD3_S(g_); g_ = LAD4_S(g_);
    float P8 = LAD5_S(g_);

    if (lane == 63){
      float vals[10] = {P0,P1,P2,P3,P4,P5,P5,P7,P8,P9};
      #pragma unroll
      for (int j = 0; j < 10; ++j)
        ((float*)&partv[half][j])[g] = vals[j];
      #pragma unroll
      for (int k = 0; k < 5; ++k)
        xpub_s[g][wbase + k] = sx[k] + bq[k];
    }
    __syncthreads();   // the ONLY barrier: partials + next-step x-parts

    // ---- combine partials + activations + cell (every lane, every wave) ----
    float4 eL = partv[0][lane];
    float4 eH = partv[1][lane];
    float E0 = fmaf(sig, eH.x, eL.x);
    float E1 = fmaf(sig, eH.y, eL.y);
    float E2 = fmaf(sig, eH.z, eL.z);
    float E3 = fmaf(sig, eH.w, eL.w);
    float fv = 1.f / (1.f + __expf(-E0));
    float iv = 1.f / (1.f + __expf(-E1));
    float e2g = __expf(2.f * E2);
    float gv = (e2g - 1.f) / (e2g + 1.f);
    float ov = 1.f / (1.f + __expf(-E3));
    c = fmaf(fv, c, iv * gv);
    float e2c = __expf(2.f * c);
    h = ov * ((e2c - 1.f) / (e2c + 1.f));

    if (wv == 0 && lane < NH)
      out[((size_t)t * BATCH + b) * NH + lane] = h;
  }

  // hT, cT
  if (wv == 0 && lane < NH){
    const size_t ysN = (size_t)T_STEPS * BATCH * NH;
    out[ysN + (size_t)b * NH + lane]                      = h;
    out[ysN + (size_t)BATCH * NH + (size_t)b * NH + lane] = c;
  }
}

extern "C" void kernel_launch(void* const* d_in, const int* in_sizes, int n_in,
                              void* d_out, int out_size, void* d_ws, size_t ws_size,
                              hipStream_t stream)
{
  qlstm_kernel<<<BATCH, 512, 0, stream>>>(
      (const float*)d_in[0], (const float*)d_in[1],
      (const float*)d_in[2], (const float*)d_in[3],
      (const float*)d_in[4], (const float*)d_in[5],
      (const float*)d_in[6], (const float*)d_in[7],
      (const float*)d_in[8], (const float*)d_in[9],
      (float*)d_out);
}

// Round 14
// 753.836 us; speedup vs baseline: 1.0754x; 1.0754x over previous
//
#include <hip/hip_runtime.h>
#include <math.h>

#define T_STEPS 256
#define BATCH   256
#define DDIM    128
#define NH      10

typedef float v2f __attribute__((ext_vector_type(2)));
__device__ __forceinline__ v2f sp(float x){ v2f r; r.x = x; r.y = x; return r; }
#define PKFMA(a,b,c) __builtin_elementwise_fma((a),(b),(c))

// ---------- DPP helpers (VALU pipe) ----------
template<int CTRL, int RMASK, int BMASK>
__device__ __forceinline__ float dppz(float x){
  return __int_as_float(__builtin_amdgcn_update_dpp(
      0, __float_as_int(x), CTRL, RMASK, BMASK, true));
}
template<int CTRL>
__device__ __forceinline__ float qperm(float x){
  int xi = __float_as_int(x);
  return __int_as_float(__builtin_amdgcn_update_dpp(xi, xi, CTRL, 0xF, 0xF, false));
}
__device__ __forceinline__ float rdlane(float v, int l){
  return __int_as_float(__builtin_amdgcn_readlane(__float_as_int(v), l));
}
// quad-perm xor (1 DPP): xor2 = 0x4E, xor1 = 0xB1 (proven baseline/R5)
__device__ __forceinline__ float qp2(float x){ return qperm<0x4E>(x); }
__device__ __forceinline__ float qp1(float x){ return qperm<0xB1>(x); }
// xor-4 / xor-8 within a 16-lane row, 2 DPP (proven baseline/R1)
__device__ __forceinline__ float lane_xor4(float x){
  int xi = __float_as_int(x);
  int t = __builtin_amdgcn_update_dpp(xi, xi, 0x104, 0xF, 0x5, false); // row_shl:4, banks {0,2}
  t     = __builtin_amdgcn_update_dpp(t,  xi, 0x114, 0xF, 0xA, false); // row_shr:4, banks {1,3}
  return __int_as_float(t);
}
__device__ __forceinline__ float lane_xor8(float x){
  int xi = __float_as_int(x);
  int t = __builtin_amdgcn_update_dpp(xi, xi, 0x108, 0xF, 0x3, false); // row_shl:8, banks {0,1}
  t     = __builtin_amdgcn_update_dpp(t,  xi, 0x118, 0xF, 0xC, false); // row_shr:8, banks {2,3}
  return __int_as_float(t);
}

// ---------- signed ladder stages (totals land at lane 63; proven R3) ----------
template<int CTRL,int RMASK,int BMASK>
__device__ __forceinline__ float lad_add(float v){ return v + dppz<CTRL,RMASK,BMASK>(v); }
template<int CTRL,int RMASK,int BMASK>
__device__ __forceinline__ float lad_sub(float v){ return dppz<CTRL,RMASK,BMASK>(v) - v; }
#define LAD0_A(v) lad_add<0x111,0xF,0xF>(v)
#define LAD0_S(v) lad_sub<0x111,0xF,0xF>(v)
#define LAD1_A(v) lad_add<0x112,0xF,0xF>(v)
#define LAD1_S(v) lad_sub<0x112,0xF,0xF>(v)
#define LAD2_A(v) lad_add<0x114,0xF,0xE>(v)
#define LAD2_S(v) lad_sub<0x114,0xF,0xE>(v)
#define LAD3_A(v) lad_add<0x118,0xF,0xC>(v)
#define LAD3_S(v) lad_sub<0x118,0xF,0xC>(v)
#define LAD4_A(v) lad_add<0x142,0xA,0xF>(v)
#define LAD4_S(v) lad_sub<0x142,0xA,0xF>(v)
#define LAD5_A(v) lad_add<0x143,0xC,0xF>(v)
#define LAD5_S(v) lad_sub<0x143,0xC,0xF>(v)

// ---------- ds-pipe fetchers ----------
__device__ __forceinline__ float dsx32(float x){ return __shfl_xor(x, 32, 64); }
__device__ __forceinline__ float dsx16(float x){
  return __int_as_float(__builtin_amdgcn_ds_swizzle(__float_as_int(x), 0x401F));
}

#define NK 4   // 4 packed pairs = 8 complex amps per lane (half statevector)

// ---- tau-form RX: cosines folded into phase constants; ONE pk-FMA/output.
#define RX_LANE_T(FETCH, tv)                                                   \
  { const v2f tt_ = sp(tv), nt_ = sp(-(tv));                                   \
    _Pragma("unroll")                                                          \
    for (int k = 0; k < NK; ++k){                                              \
      v2f oa, ob;                                                              \
      oa.x = FETCH(RE[k].x); oa.y = FETCH(RE[k].y);                            \
      ob.x = FETCH(IM[k].x); ob.y = FETCH(IM[k].y);                            \
      RE[k] = PKFMA(tt_, ob, RE[k]);                                           \
      IM[k] = PKFMA(nt_, oa, IM[k]);                                           \
    } }

// RX on reg bit R2 (XB=2) / R1 (XB=1): partner pair is k^XB.
template<int XB>
__device__ __forceinline__ void rx_reg_t(float tv, v2f* RE, v2f* IM){
  const v2f tt = sp(tv), nt = sp(-tv);
  v2f oR[NK], oI[NK];
  #pragma unroll
  for (int k = 0; k < NK; ++k){ oR[k] = RE[k]; oI[k] = IM[k]; }
  #pragma unroll
  for (int k = 0; k < NK; ++k){
    RE[k] = PKFMA(tt, oI[k ^ XB], RE[k]);
    IM[k] = PKFMA(nt, oR[k ^ XB], IM[k]);
  }
}
// RX on reg bit R0: partner is the swapped component of the same pair.
__device__ __forceinline__ void rx_reg9_t(float tv, v2f* RE, v2f* IM){
  const v2f tt = sp(tv), nt = sp(-tv);
  #pragma unroll
  for (int k = 0; k < NK; ++k){
    v2f oa = __builtin_shufflevector(RE[k], RE[k], 1, 0);
    v2f ob = __builtin_shufflevector(IM[k], IM[k], 1, 0);
    RE[k] = PKFMA(tt, ob, RE[k]);
    IM[k] = PKFMA(nt, oa, IM[k]);
  }
}

// 5-value wave-sum merge tree, hybrid transport (R11; RTs hidden under the
// measurement ladder). Full sums: v0@{l5=0,l4=0,l3=0}, v1@{l5=1,l4=0,l3=0},
// v2@{l5=0,l4=1,l3=0}, v3@{l5=1,l4=1,l3=0}, v4@{l3=1}.
__device__ __forceinline__ void xdots5(float xa, float xb,
                                       const v2f* WA, const v2f* WB,
                                       int l5, int l4, int l3, float* s){
  v2f xav = sp(xa), xbv = sp(xb);
  v2f p0 = PKFMA(xav, WA[0], xbv * WB[0]);
  v2f p1 = PKFMA(xav, WA[1], xbv * WB[1]);
  v2f p2 = PKFMA(xav, WA[2], xbv * WB[2]);
  float a  = p0.x + dsx32(p0.x);
  float bv = p0.y + dsx32(p0.y);
  float c  = p1.x + dsx32(p1.x);
  float d  = p1.y + dsx32(p1.y);
  float e  = p2.x + dsx32(p2.x);
  float m1 = l5 ? bv : a;
  float m2 = l5 ? d : c;
  m1 += dsx16(m1);
  m2 += dsx16(m2);
  e  += dsx16(e);
  float n1 = l4 ? m2 : m1;
  n1 += lane_xor8(n1);
  e  += lane_xor8(e);
  float p = l3 ? e : n1;
  p += lane_xor4(p);
  p += qp2(p);
  p += qp1(p);
  s[0] = rdlane(p, 0);
  s[1] = rdlane(p, 32);
  s[2] = rdlane(p, 16);
  s[3] = rdlane(p, 48);
  s[4] = rdlane(p, 8);
}

// ================= R12 layout (best measured: 756.2 us) =================
// Wave pair per gate: 512 amps/wave = 64 lanes x 8 regs (4 v2f pairs).
// Wires 0..5 -> lane bits 5..0, wire 6 -> wave bit, wires 7,8,9 -> reg bits
// 2,1,0 (R0 = packed component). 1 barrier/step.
// Wires 6 AND 0 applied FIRST on the product state, folded into a 4-term
// build (own, W-flip, L5-flip, both) with init-time D6/D0/D60 constants;
// build selection via readlane+cndmask. One ds RX stage (xor16); wires 2..5
// DPP; reg wires interleaved. R13's permlane16 variant REGRESSED (+55 us:
// swap writes a reg pair -> 4-5 instr/fetch + broken pk scheduling); this
// balance is the measured optimum of the 7 structures tried (750+-10 basin).
__global__ void __launch_bounds__(512)
__attribute__((amdgpu_waves_per_eu(2)))
qlstm_kernel(const float* __restrict__ inp, const float* __restrict__ rxp,
             const float* __restrict__ Wf, const float* __restrict__ bf,
             const float* __restrict__ Wi, const float* __restrict__ bi,
             const float* __restrict__ Wg, const float* __restrict__ bg,
             const float* __restrict__ Wo, const float* __restrict__ bo,
             float* __restrict__ out)
{
  const int b    = blockIdx.x;
  const int tid  = threadIdx.x;
  const int wv   = tid >> 6;        // 0..7
  const int g    = wv >> 1;         // gate 0..3 (f,i,g,o)
  const int half = wv & 1;          // statevector half (wire-6 / wave bit)
  const int lane = tid & 63;

  // measurement partials, transposed: partv[half][j].{x,y,z,w} = gate f,i,g,o
  __shared__ float4 partv[2][64];
  // published x-part pre-activations (incl. bias), xpub_s[g][wire]
  __shared__ float xpub_s[4][16];
  ((float*)partv)[tid] = 0.f;       // 2*64*4 = 512 = blockDim
  if (tid < 64) ((float*)xpub_s)[tid] = 0.f;

  const float* Wp = (g == 0) ? Wf : (g == 1) ? Wi : (g == 2) ? Wg : Wo;
  const float* bp = (g == 0) ? bf : (g == 1) ? bi : (g == 2) ? bg : bo;

  // Pre-scale weights by 0.5 (half-angle) * 1/(2pi) (v_cos takes revolutions).
  const float WSC = 0.07957747154594767f;   // 1/(4*pi)

  // x-dot weights for this half's 5 owned wires (wbase..wbase+4)
  const int wbase = half * 5;
  v2f WA[3], WB[3];
  float bq[5];
  #pragma unroll
  for (int k = 0; k < 5; ++k) bq[k] = WSC * (bp[wbase + k] + rxp[wbase + k]);
  #pragma unroll
  for (int j = 0; j < 3; ++j){
    const int w0 = wbase + 2*j, w1 = wbase + 2*j + 1;
    WA[j].x = WSC * Wp[w0*138 + lane];
    WB[j].x = WSC * Wp[w0*138 + 64 + lane];
    if (2*j + 1 < 5){
      WA[j].y = WSC * Wp[w1*138 + lane];
      WB[j].y = WSC * Wp[w1*138 + 64 + lane];
    } else { WA[j].y = 0.f; WB[j].y = 0.f; }
  }
  // transposed h-weights: lane w AND lane 16+w hold W[w][128+j] (the high
  // group recomputes the same th for the sin path).
  const int trigAct = (lane < NH) || (lane >= 16 && lane < 16 + NH);
  float wCT[NH];
  {
    const int row = trigAct ? (lane & 15) : 0;
    #pragma unroll
    for (int j = 0; j < NH; ++j){
      float v = WSC * Wp[row*138 + 128 + j];
      wCT[j] = trigAct ? v : 0.f;
    }
  }
  // sin shift: lanes with bit4 set evaluate cos(th - 0.25rev) = sin(th)
  const float shift = ((lane >> 4) & 1) ? -0.25f : 0.f;

  // tau-form RX constants: tq[w] = tan(rxp[w]/2); PC = prod cos(rxp[w]/2)
  float tq[NH];
  float PC = 1.f;
  #pragma unroll
  for (int w = 0; w < NH; ++w){
    float th = 0.5f * rxp[w];
    float cw = cosf(th), sw = sinf(th);
    PC *= cw;
    tq[w] = sw / cw;
  }

  // ---- hoisted lane/wave constants ----
  const int l5 = (lane>>5)&1, l4 = (lane>>4)&1, l3 = (lane>>3)&1;
  const int l2 = (lane>>2)&1, l1 = (lane>>1)&1, l0 = lane&1;
  const int pb2 = l4^l3, pb3 = l3^l2, pb4 = l2^l1, pb5 = l1^l0;
  const int a0 = l5, a1 = l5^l4;
  const int a6w = l0 ^ half;                       // beta6
  const int n_base = pb2 + pb3 + pb4 + pb5 + a6w;

  // phase constants (-i)^k per reg (step-invariant), packed over R0, scaled
  // by PC. Fold constants for the two pre-applied rotations:
  //   D6*: wire-6 (wave-bit) partner, sign s6 = (l0^R2)? + : -  [R7-proven]
  //   D0*: wire-0 (L5) partner,      sign s0 = l4? + : -
  //   D60*: both flipped, factor -tau6*tau0*s6*s0 on (CRE,CIM)
  v2f CRE[NK], CIM[NK], D6RE[NK], D6IM[NK];
  v2f D0RE[NK], D0IM[NK], D60RE[NK], D60IM[NK];
  #pragma unroll
  for (int r = 0; r < 2*NK; ++r){
    const int R0 = r&1, R1 = (r>>1)&1, R2 = (r>>2)&1;
    int k = (n_base + (a0^R0) + (a1^R0) + (half^R2) + (R2^R1) + (R1^R0)) & 3;
    float cr = (k==0) ? PC : (k==2) ? -PC : 0.f;
    float ci = (k==1) ? -PC : (k==3) ? PC : 0.f;
    float s6s = ((l0 ^ R2) & 1) ? 1.f : -1.f;
    float s0s = l4 ? 1.f : -1.f;
    float d6re =  tq[6]*s6s*ci,  d6im = -tq[6]*s6s*cr;
    float d0re =  tq[0]*s0s*ci,  d0im = -tq[0]*s0s*cr;
    float t60  = -tq[6]*tq[0]*s6s*s0s;
    float d60re = t60*cr, d60im = t60*ci;
    if (R0){ CRE[r>>1].y = cr;   CIM[r>>1].y = ci;
             D6RE[r>>1].y = d6re; D6IM[r>>1].y = d6im;
             D0RE[r>>1].y = d0re; D0IM[r>>1].y = d0im;
             D60RE[r>>1].y = d60re; D60IM[r>>1].y = d60im; }
    else   { CRE[r>>1].x = cr;   CIM[r>>1].x = ci;
             D6RE[r>>1].x = d6re; D6IM[r>>1].x = d6im;
             D0RE[r>>1].x = d0re; D0IM[r>>1].x = d0im;
             D60RE[r>>1].x = d60re; D60IM[r>>1].x = d60im; }
  }

  // wave-sign at combine: sigma = -1 for hidden units {0, 6..9}
  const float sig = (lane == 0 || lane >= 6) ? -1.f : 1.f;

  float h = 0.f, c = 0.f;   // lane j holds h_j, c_j redundantly in every wave

  const float* x0 = inp + (size_t)b * DDIM;
  float xa = x0[lane];
  float xb = x0[64 + lane];

  // publish x-part pre-activations for step 0
  {
    float sx[5];
    xdots5(xa, xb, WA, WB, l5, l4, l3, sx);
    if (lane == 63){
      #pragma unroll
      for (int k = 0; k < 5; ++k) xpub_s[g][wbase + k] = sx[k] + bq[k];
    }
  }
  __syncthreads();

  #pragma unroll 1
  for (int t = 0; t < T_STEPS; ++t){
    if (t + 1 < T_STEPS){
      const float* nx = inp + ((size_t)(t+1) * BATCH + b) * DDIM;
      xa = nx[lane];
      xb = nx[64 + lane];
    }

    // ---- angles: lanes 0..9 -> cos, lanes 16..25 -> sin (same th, -0.25) ----
    float cA;
    {
      float xr = xpub_s[g][lane & 15];
      float hdA = rdlane(h, 0) * wCT[0];
      float hdB = rdlane(h, 1) * wCT[1];
      hdA = fmaf(rdlane(h, 2), wCT[2], hdA);
      hdB = fmaf(rdlane(h, 3), wCT[3], hdB);
      hdA = fmaf(rdlane(h, 4), wCT[4], hdA);
      hdB = fmaf(rdlane(h, 5), wCT[5], hdB);
      hdA = fmaf(rdlane(h, 6), wCT[6], hdA);
      hdB = fmaf(rdlane(h, 7), wCT[7], hdB);
      hdA = fmaf(rdlane(h, 8), wCT[8], hdA);
      hdB = fmaf(rdlane(h, 9), wCT[9], hdB);
      float th = (xr + (hdA + hdB)) + shift;
      cA = __builtin_amdgcn_cosf(th);
    }

    // ---- build factors via readlane selects (no ds round trip) ----
    float cs0 = rdlane(cA, 0), sn0 = rdlane(cA, 16);
    float cs1 = rdlane(cA, 1), sn1 = rdlane(cA, 17);
    float cs2 = rdlane(cA, 2), sn2 = rdlane(cA, 18);
    float cs3 = rdlane(cA, 3), sn3 = rdlane(cA, 19);
    float cs4 = rdlane(cA, 4), sn4 = rdlane(cA, 20);
    float cs5 = rdlane(cA, 5), sn5 = rdlane(cA, 21);
    float cs6 = rdlane(cA, 6), sn6 = rdlane(cA, 22);
    float f2  = pb2 ? sn2 : cs2;
    float f3  = pb3 ? sn3 : cs3;
    float f4  = pb4 ? sn4 : cs4;
    float f5  = pb5 ? sn5 : cs5;
    float w6o = a6w ? sn6 : cs6;
    float w6p = a6w ? cs6 : sn6;
    float q0  = (a0 ? sn0 : cs0) * (a1 ? sn1 : cs1);
    float q1  = (a0 ? cs0 : sn0) * (a1 ? cs1 : sn1);
    float m2345b = (f2*f3)*(f4*f5);
    float mo = m2345b * w6o;
    float mp = m2345b * w6p;
    v2f ZZ; ZZ.x = mo * q0; ZZ.y = mo * q1;
    v2f ZP; ZP.x = mp * q0; ZP.y = mp * q1;
    v2f ZZs = __builtin_shufflevector(ZZ, ZZ, 1, 0);   // L5-flip: q0<->q1
    v2f ZPs = __builtin_shufflevector(ZP, ZP, 1, 0);

    float u7  = rdlane(cA, 7 + 16*half);
    float u7b = rdlane(cA, 23 - 16*half);
    float c8  = rdlane(cA, 8);
    float s8  = rdlane(cA, 24);
    float c9  = rdlane(cA, 9);
    float s9  = rdlane(cA, 25);
    float t78[4];
    t78[0] = u7  * c8;   // k=0: R2=0,R1=0
    t78[1] = u7  * s8;   // k=1: R2=0,R1=1
    t78[2] = u7b * s8;   // k=2: R2=1,R1=0
    t78[3] = u7b * c8;   // k=3: R2=1,R1=1
    v2f s9a; s9a.x = c9; s9a.y = s9;   // k even: b9 = R1^R0 = (0,1)
    v2f s9b; s9b.x = s9; s9b.y = c9;   // k odd:  b9 = (1,0)

    // ---- 4-term build: own + wire-6 partner + wire-0 partner + both ----
    v2f RE[NK], IM[NK];
    #pragma unroll
    for (int k = 0; k < NK; ++k){
      v2f s9v = (k & 1) ? s9b : s9a;
      v2f G   = sp(t78[k])     * s9v;
      v2f Gp  = sp(t78[k ^ 3]) * s9v;   // beta7 flip (wire-6 partner)
      v2f M   = G  * ZZ;
      v2f Mp6 = Gp * ZP;
      v2f M0  = G  * ZZs;
      v2f M60 = Gp * ZPs;
      RE[k] = PKFMA(M60, D60RE[k],
              PKFMA(M0,  D0RE[k],
              PKFMA(Mp6, D6RE[k], M * CRE[k])));
      IM[k] = PKFMA(M60, D60IM[k],
              PKFMA(M0,  D0IM[k],
              PKFMA(Mp6, D6IM[k], M * CIM[k])));
    }

    // ---- RX(p), tau-form: ONE ds stage (xor16), DPP wires 2..5, reg wires
    // interleaved so their pk-FMAs hide the lgkm wait ----
    RX_LANE_T(dsx16, tq[1])
    rx_reg_t<2>(tq[7], RE, IM);
    rx_reg_t<1>(tq[8], RE, IM);
    RX_LANE_T(lane_xor8, tq[2])
    rx_reg9_t  (tq[9], RE, IM);
    RX_LANE_T(lane_xor4, tq[3])
    RX_LANE_T(qp2, tq[4])
    RX_LANE_T(qp1, tq[5])

    // ---- shadow: x-part dots for step t+1 (uses prefetched x) ----
    float sx[5];
    xdots5(xa, xb, WA, WB, l5, l4, l3, sx);

    // ---- PauliZ partials: packed |psi|^2 + shared pair-tree ----
    v2f Pk[NK];
    #pragma unroll
    for (int k = 0; k < NK; ++k) Pk[k] = PKFMA(RE[k], RE[k], IM[k] * IM[k]);
    float A0 = Pk[0].x + Pk[0].y, A1 = Pk[1].x + Pk[1].y;
    float A2 = Pk[2].x + Pk[2].y, A3 = Pk[3].x + Pk[3].y;
    float B0 = Pk[0].x - Pk[0].y, B1 = Pk[1].x - Pk[1].y;
    float B2 = Pk[2].x - Pk[2].y, B3 = Pk[3].x - Pk[3].y;
    float su = A0 + A1, sv = A2 + A3;
    float tot = su + sv;                 // plain sum
    float q4  = su - sv;                 // sign on R2
    float q6  = (A0 - A1) - (A2 - A3);   // sign parity of R2^R1 mask 0x6
    float q7  = (B0 - B1) - (B2 - B3);   // sign parity of mask 0x7

    // ---- shared signed-ladder reductions (sign masks encoded as add/sub) ----
    float a0p = LAD0_A(tot);
    float a0m = LAD0_S(tot);
    float b1pp = LAD1_A(a0p);
    float b1pm = LAD1_S(a0p);
    float b1mm = LAD1_S(a0m);
    float c2ppp = LAD2_A(b1pp);
    float c2ppm = LAD2_S(b1pp);
    float c2pmm = LAD2_S(b1pm);
    float c2mmm = LAD2_S(b1mm);
    float d1 = LAD3_A(c2ppp);   // P1: ++++ then --
    float d2 = LAD3_S(c2ppp);   // P2: +++-
    float d3 = LAD3_S(c2ppm);   // P3: ++--
    float d4 = LAD3_S(c2pmm);   // P4: +---
    float d5 = LAD3_S(c2mmm);   // P5: ----
    float P1 = LAD5_S(LAD4_S(d1));
    float P2 = LAD5_S(LAD4_S(d2));
    float P3 = LAD5_S(LAD4_S(d3));
    float P4 = LAD5_S(LAD4_S(d4));
    float P5 = LAD5_S(LAD4_S(d5));   // serves S5 (sigma +) and S6 (sigma -)
    // q7: P9 = all-minus (mask 0x3F); P0 = minus bits0-4, plus bit5 (0x1F)
    float e = LAD0_S(q7);
    e = LAD1_S(e); e = LAD2_S(e); e = LAD3_S(e); e = LAD4_S(e);
    float P9 = LAD5_S(e);
    float P0 = LAD5_A(e);
    // q4, q6: all-minus (mask 0x3F)
    float f_ = LAD0_S(q4);
    f_ = LAD1_S(f_); f_ = LAD2_S(f_); f_ = LAD3_S(f_); f_ = LAD4_S(f_);
    float P7 = LAD5_S(f_);
    float g_ = LAD0_S(q6);
    g_ = LAD1_S(g_); g_ = LAD2_S(g_); g_ = LAD3_S(g_); g_ = LAD4_S(g_);
    float P8 = LAD5_S(g_);

    if (lane == 63){
      float vals[10] = {P0,P1,P2,P3,P4,P5,P5,P7,P8,P9};
      #pragma unroll
      for (int j = 0; j < 10; ++j)
        ((float*)&partv[half][j])[g] = vals[j];
      #pragma unroll
      for (int k = 0; k < 5; ++k)
        xpub_s[g][wbase + k] = sx[k] + bq[k];
    }
    __syncthreads();   // the ONLY barrier: partials + next-step x-parts

    // ---- combine partials + activations + cell (every lane, every wave) ----
    float4 eL = partv[0][lane];
    float4 eH = partv[1][lane];
    float E0 = fmaf(sig, eH.x, eL.x);
    float E1 = fmaf(sig, eH.y, eL.y);
    float E2 = fmaf(sig, eH.z, eL.z);
    float E3 = fmaf(sig, eH.w, eL.w);
    float fv = 1.f / (1.f + __expf(-E0));
    float iv = 1.f / (1.f + __expf(-E1));
    float e2g = __expf(2.f * E2);
    float gv = (e2g - 1.f) / (e2g + 1.f);
    float ov = 1.f / (1.f + __expf(-E3));
    c = fmaf(fv, c, iv * gv);
    float e2c = __expf(2.f * c);
    h = ov * ((e2c - 1.f) / (e2c + 1.f));

    if (wv == 0 && lane < NH)
      out[((size_t)t * BATCH + b) * NH + lane] = h;
  }

  // hT, cT
  if (wv == 0 && lane < NH){
    const size_t ysN = (size_t)T_STEPS * BATCH * NH;
    out[ysN + (size_t)b * NH + lane]                      = h;
    out[ysN + (size_t)BATCH * NH + (size_t)b * NH + lane] = c;
  }
}

extern "C" void kernel_launch(void* const* d_in, const int* in_sizes, int n_in,
                              void* d_out, int out_size, void* d_ws, size_t ws_size,
                              hipStream_t stream)
{
  qlstm_kernel<<<BATCH, 512, 0, stream>>>(
      (const float*)d_in[0], (const float*)d_in[1],
      (const float*)d_in[2], (const float*)d_in[3],
      (const float*)d_in[4], (const float*)d_in[5],
      (const float*)d_in[6], (const float*)d_in[7],
      (const float*)d_in[8], (const float*)d_in[9],
      (float*)d_out);
}